// Round 17
// baseline (93.014 us; speedup 1.0000x reference)
//
#include <hip/hip_runtime.h>
#include <math.h>
#include <stdint.h>

typedef unsigned short u16;
typedef __bf16 bf16x8 __attribute__((ext_vector_type(8)));
typedef float f32x4 __attribute__((ext_vector_type(4)));

constexpr int Bb = 2, Ss = 2048, Dd = 1024, Hh = 16, Hd = 64, Win = 256;
constexpr int Mtot = Bb * Ss;   // 4096

// ---------- helpers ----------
__device__ __forceinline__ u16 f2bf(float f) {
    uint32_t u = __float_as_uint(f);
    u += 0x7fff + ((u >> 16) & 1);   // RNE
    return (u16)(u >> 16);
}

__device__ __forceinline__ void gload16(const void* g, void* l) {
    __builtin_amdgcn_global_load_lds(
        (const __attribute__((address_space(1))) uint32_t*)g,
        (__attribute__((address_space(3))) uint32_t*)l, 16, 0, 0);
}

// ---------- merged prep: x->bf16, 4 weights->bf16, rope cs table (1 launch) ----------
__global__ void prep(const float* __restrict__ x,
                     const float* __restrict__ Wq, const float* __restrict__ Wk,
                     const float* __restrict__ Wv, const float* __restrict__ Wo,
                     u16* __restrict__ xb,
                     u16* __restrict__ wqb, u16* __restrict__ wkb,
                     u16* __restrict__ wvb, u16* __restrict__ wob,
                     float2* __restrict__ cs) {
    const int bid = blockIdx.x;
    if (bid < 8192) {
        const float* s;
        u16* d;
        int i;
        if (bid < 4096) {
            s = x; d = xb; i = bid * 256 + threadIdx.x;
        } else {
            int wsel = (bid - 4096) >> 10;
            i = ((bid - 4096) & 1023) * 256 + threadIdx.x;
            s = (wsel == 0) ? Wq : (wsel == 1) ? Wk : (wsel == 2) ? Wv : Wo;
            d = (wsel == 0) ? wqb : (wsel == 1) ? wkb : (wsel == 2) ? wvb : wob;
        }
        float4 v = reinterpret_cast<const float4*>(s)[i];
        ushort4 o;
        o.x = f2bf(v.x); o.y = f2bf(v.y); o.z = f2bf(v.z); o.w = f2bf(v.w);
        reinterpret_cast<ushort4*>(d)[i] = o;
    } else {
        int i = (bid - 8192) * 256 + threadIdx.x;    // over Ss*64
        int s = i >> 6, d = i & 63;
        float invf = powf(10000.0f, -(float)(d & 31) / 32.0f);
        float ang = (float)s * invf;
        float2 c; c.x = cosf(ang); c.y = sinf(ang);
        cs[i] = c;
    }
}

// ---------- serial 2-barrier 128x128 bf16 MFMA GEMM, BK=64, 8 waves (r11) ----------
// C[m][n] = sum_k Am[m][k] * Bm[n][k]. 512 thr = 8 waves (2M x 4N), each wave
// 64x32 per frag-set, 16 MFMA/iter, 16 iters. Proven best config (r11: 40.3us).
// Swizzle (conflict-free involution): LDS granule slot s at row r holds source
// granule s^(r&7); frag read slot = (ks*4+kg)^(r&7).
// MODE 0: z<2 -> Q/K with fused RoPE, write [bh][s][64];
//         z==2 -> V^T (Am=Wv, Bm=x swapped), write Vt[bh][d][s] (no rope).
// MODE 1: fp32 [M][N].
template <int MODE>
__global__ __launch_bounds__(512) void gemm_k(
    const u16* __restrict__ A,
    const u16* __restrict__ B0, const u16* __restrict__ B1, const u16* __restrict__ B2,
    void* __restrict__ C0, void* __restrict__ C1, void* __restrict__ C2,
    const float2* __restrict__ cs,
    int M, int N, int Kd)
{
    const int z = blockIdx.z;
    const u16* Am;
    const u16* Bm;
    int m0, n0;
    if (MODE == 0 && z == 2) {           // V^T = Wv @ x^T
        Am = B2; Bm = A;
        m0 = blockIdx.y * 128;           // over Wv rows (1024)
        n0 = blockIdx.x * 128;           // over tokens (4096)
    } else {
        Am = A;
        Bm = (z == 0) ? B0 : (z == 1) ? B1 : B2;
        m0 = blockIdx.x * 128;
        n0 = blockIdx.y * 128;
    }
    void* C = (z == 0) ? C0 : (z == 1) ? C1 : C2;

    __shared__ u16 sA[128 * 64];
    __shared__ u16 sB[128 * 64];

    const int t = threadIdx.x, l = t & 63, w = t >> 6;
    const int wm = w >> 2, wn = w & 3;            // 2M x 4N waves
    const int lr = l & 15, kg = l >> 4;

    f32x4 acc[4][2] = {};

    for (int k0 = 0; k0 < Kd; k0 += 64) {
        __syncthreads();
        // stage 2x16KB: linear dest (DMA lane rule), source granule pre-swizzled
#pragma unroll
        for (int p = 0; p < 2; ++p) {
            int i = p * 512 + t;
            int r = i >> 3;                       // row 0..127
            int gg = (i & 7) ^ (r & 7);           // source 16B-granule
            gload16(Am + (size_t)(m0 + r) * Kd + k0 + gg * 8, &sA[i * 8]);
            gload16(Bm + (size_t)(n0 + r) * Kd + k0 + gg * 8, &sB[i * 8]);
        }
        __syncthreads();

        bf16x8 af[4][2], bfr[2][2];
#pragma unroll
        for (int im = 0; im < 4; ++im) {
            int r = wm * 64 + im * 16 + lr;
#pragma unroll
            for (int ks = 0; ks < 2; ++ks) {
                int slot = (ks * 4 + kg) ^ (r & 7);
                af[im][ks] = *reinterpret_cast<const bf16x8*>(&sA[r * 64 + slot * 8]);
            }
        }
#pragma unroll
        for (int in = 0; in < 2; ++in) {
            int r = wn * 32 + in * 16 + lr;
#pragma unroll
            for (int ks = 0; ks < 2; ++ks) {
                int slot = (ks * 4 + kg) ^ (r & 7);
                bfr[in][ks] = *reinterpret_cast<const bf16x8*>(&sB[r * 64 + slot * 8]);
            }
        }
#pragma unroll
        for (int im = 0; im < 4; ++im)
#pragma unroll
            for (int in = 0; in < 2; ++in) {
                acc[im][in] = __builtin_amdgcn_mfma_f32_16x16x32_bf16(
                    af[im][0], bfr[in][0], acc[im][in], 0, 0, 0);
                acc[im][in] = __builtin_amdgcn_mfma_f32_16x16x32_bf16(
                    af[im][1], bfr[in][1], acc[im][in], 0, 0, 0);
            }
    }

#pragma unroll
    for (int im = 0; im < 4; ++im) {
#pragma unroll
        for (int in = 0; in < 2; ++in) {
#pragma unroll
            for (int j = 0; j < 4; ++j) {
                int row = m0 + wm * 64 + im * 16 + kg * 4 + j;
                int col = n0 + wn * 32 + in * 16 + lr;
                float v = acc[im][in][j];
                if (MODE == 0) {
                    if (z == 2) {
                        // V^T: row = h*64+d over 1024, col = b*2048+s over 4096
                        int h = row >> 6, d = row & 63;
                        int b = col >> 11, s = col & 2047;
                        ((u16*)C)[((size_t)((b * 16 + h) * 64 + d)) * 2048 + s] = f2bf(v);
                    } else {
                        // Q/K with fused RoPE; partner col^1 lives in lane l^1
                        float vp = __shfl_xor(v, 1);
                        int b = row >> 11, s = row & 2047;
                        int h = col >> 6, d = col & 63;
                        float2 c2 = cs[s * 64 + d];
                        float outv = (col & 1) ? (v * c2.x + vp * c2.y)
                                               : (v * c2.x - vp * c2.y);
                        ((u16*)C)[(((size_t)(b * 16 + h)) * 2048 + s) * 64 + d] = f2bf(outv);
                    }
                } else {
                    ((float*)C)[(size_t)row * N + col] = v;
                }
            }
        }
    }
}

// ---------- MFMA flash attention, window=256 — QBLK=128, KVBLK=128 ----------
// r16 per-key math byte-for-byte (mask always, __expf, -1e20 guard). KVBLK=128:
// 3 kv-tiles [max(0,qt-2)..qt] instead of 6 -> barriers 12->6, rescale/shfl
// passes halved, same staged bytes & MFMA count. LDS 64 KB (2 blocks/CU, same
// as before since grid = 2/CU). Swizzles re-derived for 256B rows (sVT/sP):
// XOR field ((row&7)<<4) unchanged (row low-3 bits preserved by all layouts).
__global__ __launch_bounds__(512) void fattn(
    const u16* __restrict__ Qb, const u16* __restrict__ Kb,
    const u16* __restrict__ Vt, u16* __restrict__ O)
{
    __shared__ u16 sK[128 * 64];     // [kv][d]  128B rows
    __shared__ u16 sVT[64 * 128];    // [d][kv]  256B rows
    __shared__ u16 sP[8][16 * 128];  // per-wave [q][kv] 256B rows

    const int t = threadIdx.x, l = t & 63, w = t >> 6;
    const int lo = l & 15, hi = l >> 4;
    const int qt = blockIdx.x, bh = blockIdx.y;   // qt over Ss/128
    const int q0 = qt * 128;

    // Q A-fragments direct from global (row 128B-contiguous, 16B/lane)
    bf16x8 qf[2];
    {
        const u16* Qr = Qb + ((size_t)bh * Ss + q0 + w * 16 + lo) * 64 + hi * 8;
#pragma unroll
        for (int ck = 0; ck < 2; ++ck)
            qf[ck] = *reinterpret_cast<const bf16x8*>(Qr + ck * 32);
    }

    f32x4 o[4] = {};
    float mj[4], lj[4];
#pragma unroll
    for (int j = 0; j < 4; ++j) { mj[j] = -1e30f; lj[j] = 0.f; }

    const int jt0 = (qt >= 2) ? qt - 2 : 0;
    for (int jt = jt0; jt <= qt; ++jt) {
        __syncthreads();
        // ---- stage K tile 16 KB: [kv 128][d 64], linear dest, src-preswizzled ----
        const char* Kg = (const char*)(Kb + ((size_t)bh * Ss + jt * 128) * 64);
#pragma unroll
        for (int p = 0; p < 2; ++p) {
            uint32_t x = (uint32_t)(p * 512 + t) * 16;
            uint32_t sx = x ^ (((x >> 7) & 7) << 4);         // row = x>>7
            gload16(Kg + sx, (char*)sK + x);
        }
        // ---- stage V^T tile 16 KB: [d 64][kv 128], global row stride 4096B ----
        const char* Vg = (const char*)(Vt + (size_t)bh * 64 * 2048 + (size_t)jt * 128);
#pragma unroll
        for (int p = 0; p < 2; ++p) {
            uint32_t x = (uint32_t)(p * 512 + t) * 16;
            uint32_t sx = x ^ (((x >> 8) & 7) << 4);         // row d = x>>8
            gload16(Vg + (size_t)(x >> 8) * 4096 + (sx & 255), (char*)sVT + x);
        }
        __syncthreads();

        // ---- QK^T: 8 nb frags cover kv 0..127 ----
        f32x4 s4[8] = {};
#pragma unroll
        for (int ck = 0; ck < 2; ++ck) {
#pragma unroll
            for (int nb = 0; nb < 8; ++nb) {
                uint32_t b = (uint32_t)(nb * 16 + lo) * 128 + ck * 64 + hi * 16;
                b ^= ((lo & 7) << 4);
                bf16x8 kf = *reinterpret_cast<const bf16x8*>((const char*)sK + b);
                s4[nb] = __builtin_amdgcn_mfma_f32_16x16x32_bf16(qf[ck], kf, s4[nb], 0, 0, 0);
            }
        }

        // ---- scale + window/causal mask ----
        const int qbase = q0 + w * 16 + hi * 4;
#pragma unroll
        for (int nb = 0; nb < 8; ++nb) {
            int k = jt * 128 + nb * 16 + lo;
#pragma unroll
            for (int j = 0; j < 4; ++j) {
                int q = qbase + j;
                float v = s4[nb][j] * 0.125f;
                bool ok = (k <= q) && (q - k < Win);
                s4[nb][j] = ok ? v : -1e30f;
            }
        }

        // ---- online softmax ----
#pragma unroll
        for (int j = 0; j < 4; ++j) {
            float tm = fmaxf(fmaxf(fmaxf(s4[0][j], s4[1][j]), fmaxf(s4[2][j], s4[3][j])),
                             fmaxf(fmaxf(s4[4][j], s4[5][j]), fmaxf(s4[6][j], s4[7][j])));
            tm = fmaxf(tm, __shfl_xor(tm, 1));
            tm = fmaxf(tm, __shfl_xor(tm, 2));
            tm = fmaxf(tm, __shfl_xor(tm, 4));
            tm = fmaxf(tm, __shfl_xor(tm, 8));
            float nm = fmaxf(fmaxf(mj[j], tm), -1e20f);
            float sc = __expf(mj[j] - nm);
            mj[j] = nm;
            lj[j] *= sc;
#pragma unroll
            for (int nb = 0; nb < 4; ++nb) o[nb][j] *= sc;
            float ps = 0.f;
#pragma unroll
            for (int nb = 0; nb < 8; ++nb) {
                float p = __expf(s4[nb][j] - nm);
                ps += p;
                s4[nb][j] = p;
            }
            lj[j] += ps;
        }

        // ---- P -> per-wave LDS (bf16, swizzled [16][128]); same-wave DS order ----
#pragma unroll
        for (int nb = 0; nb < 8; ++nb) {
#pragma unroll
            for (int j = 0; j < 4; ++j) {
                int r = hi * 4 + j;
                uint32_t b = ((uint32_t)r * 256 + (nb * 16 + lo) * 2) ^ (((uint32_t)(r & 7)) << 4);
                *(u16*)((char*)&sP[w][0] + b) = f2bf(s4[nb][j]);
            }
        }

        // ---- PV: O += P @ V, kv in 4 slices of 32 ----
#pragma unroll
        for (int ck = 0; ck < 4; ++ck) {
            uint32_t bp = ((uint32_t)lo * 256 + ck * 64 + hi * 16) ^ (((uint32_t)(lo & 7)) << 4);
            bf16x8 pa = *reinterpret_cast<const bf16x8*>((const char*)&sP[w][0] + bp);
#pragma unroll
            for (int nb = 0; nb < 4; ++nb) {
                uint32_t bb = ((uint32_t)(nb * 16 + lo) * 256 + ck * 64 + hi * 16) ^ (((uint32_t)(lo & 7)) << 4);
                bf16x8 vf = *reinterpret_cast<const bf16x8*>((const char*)sVT + bb);
                o[nb] = __builtin_amdgcn_mfma_f32_16x16x32_bf16(pa, vf, o[nb], 0, 0, 0);
            }
        }
    }

    // ---- finalize ----
#pragma unroll
    for (int j = 0; j < 4; ++j) {
        float s = lj[j];
        s += __shfl_xor(s, 1);
        s += __shfl_xor(s, 2);
        s += __shfl_xor(s, 4);
        s += __shfl_xor(s, 8);
        lj[j] = 1.0f / s;
    }
    const int bq = bh >> 4, h = bh & 15;
#pragma unroll
    for (int nb = 0; nb < 4; ++nb) {
#pragma unroll
        for (int j = 0; j < 4; ++j) {
            int q = q0 + w * 16 + hi * 4 + j;
            int d = nb * 16 + lo;
            O[((size_t)(bq * Ss + q)) * Dd + h * 64 + d] = f2bf(o[nb][j] * lj[j]);
        }
    }
}

// ---------- launch ----------
extern "C" void kernel_launch(void* const* d_in, const int* in_sizes, int n_in,
                              void* d_out, int out_size, void* d_ws, size_t ws_size,
                              hipStream_t stream) {
    const float* x  = (const float*)d_in[0];
    const float* Wq = (const float*)d_in[1];
    const float* Wk = (const float*)d_in[2];
    const float* Wv = (const float*)d_in[3];
    const float* Wo = (const float*)d_in[4];
    float* out = (float*)d_out;

    char* ws = (char*)d_ws;
    size_t off = 0;
    auto carve = [&](size_t bytes) -> char* {
        char* p = ws + off;
        off += (bytes + 255) & ~(size_t)255;
        return p;
    };
    float2* cs = (float2*)carve((size_t)Ss * 64 * 8);
    u16* xb  = (u16*)carve((size_t)Mtot * Dd * 2);
    u16* wqb = (u16*)carve((size_t)Dd * Dd * 2);
    u16* wkb = (u16*)carve((size_t)Dd * Dd * 2);
    u16* wvb = (u16*)carve((size_t)Dd * Dd * 2);
    u16* wob = (u16*)carve((size_t)Dd * Dd * 2);
    u16* Qbb = (u16*)carve((size_t)Mtot * Dd * 2);
    u16* Kbb = (u16*)carve((size_t)Mtot * Dd * 2);
    u16* Vtb = (u16*)carve((size_t)Mtot * Dd * 2);   // V^T: [bh][d][s]
    u16* attb = (u16*)carve((size_t)Mtot * Dd * 2);

    prep<<<8704, 256, 0, stream>>>(x, Wq, Wk, Wv, Wo,
                                   xb, wqb, wkb, wvb, wob, cs);

    gemm_k<0><<<dim3(Mtot / 128, Dd / 128, 3), 512, 0, stream>>>(
        xb, wqb, wkb, wvb, Qbb, Kbb, Vtb, cs, Mtot, Dd, Dd);

    fattn<<<dim3(Ss / 128, Bb * Hh), 512, 0, stream>>>(Qbb, Kbb, Vtb, attb);

    gemm_k<1><<<dim3(Mtot / 128, Dd / 128, 1), 512, 0, stream>>>(
        attb, wob, wob, wob, out, out, out, nullptr, Mtot, Dd, Dd);
}

// Round 18
// 88.717 us; speedup vs baseline: 1.0484x; 1.0484x over previous
//
#include <hip/hip_runtime.h>
#include <math.h>
#include <stdint.h>

typedef unsigned short u16;
typedef __bf16 bf16x8 __attribute__((ext_vector_type(8)));
typedef float f32x4 __attribute__((ext_vector_type(4)));

constexpr int Bb = 2, Ss = 2048, Dd = 1024, Hh = 16, Hd = 64, Win = 256;
constexpr int Mtot = Bb * Ss;   // 4096

// ---------- helpers ----------
__device__ __forceinline__ u16 f2bf(float f) {
    uint32_t u = __float_as_uint(f);
    u += 0x7fff + ((u >> 16) & 1);   // RNE
    return (u16)(u >> 16);
}

__device__ __forceinline__ void gload16(const void* g, void* l) {
    __builtin_amdgcn_global_load_lds(
        (const __attribute__((address_space(1))) uint32_t*)g,
        (__attribute__((address_space(3))) uint32_t*)l, 16, 0, 0);
}

// ---------- merged prep: x->bf16, 4 weights->bf16, rope cs table (1 launch) ----------
__global__ void prep(const float* __restrict__ x,
                     const float* __restrict__ Wq, const float* __restrict__ Wk,
                     const float* __restrict__ Wv, const float* __restrict__ Wo,
                     u16* __restrict__ xb,
                     u16* __restrict__ wqb, u16* __restrict__ wkb,
                     u16* __restrict__ wvb, u16* __restrict__ wob,
                     float2* __restrict__ cs) {
    const int bid = blockIdx.x;
    if (bid < 8192) {
        const float* s;
        u16* d;
        int i;
        if (bid < 4096) {
            s = x; d = xb; i = bid * 256 + threadIdx.x;
        } else {
            int wsel = (bid - 4096) >> 10;
            i = ((bid - 4096) & 1023) * 256 + threadIdx.x;
            s = (wsel == 0) ? Wq : (wsel == 1) ? Wk : (wsel == 2) ? Wv : Wo;
            d = (wsel == 0) ? wqb : (wsel == 1) ? wkb : (wsel == 2) ? wvb : wob;
        }
        float4 v = reinterpret_cast<const float4*>(s)[i];
        ushort4 o;
        o.x = f2bf(v.x); o.y = f2bf(v.y); o.z = f2bf(v.z); o.w = f2bf(v.w);
        reinterpret_cast<ushort4*>(d)[i] = o;
    } else {
        int i = (bid - 8192) * 256 + threadIdx.x;    // over Ss*64
        int s = i >> 6, d = i & 63;
        float invf = powf(10000.0f, -(float)(d & 31) / 32.0f);
        float ang = (float)s * invf;
        float2 c; c.x = cosf(ang); c.y = sinf(ang);
        cs[i] = c;
    }
}

// ---------- serial 2-barrier 128x128 bf16 MFMA GEMM, BK=64, 8 waves (r11) ----------
// C[m][n] = sum_k Am[m][k] * Bm[n][k]. 512 thr = 8 waves (2M x 4N), each wave
// 64x32 per frag-set, 16 MFMA/iter, 16 iters. Proven best config (r11: 40.3us).
// Swizzle (conflict-free involution): LDS granule slot s at row r holds source
// granule s^(r&7); frag read slot = (ks*4+kg)^(r&7).
// MODE 0: z<2 -> Q/K with fused RoPE, write [bh][s][64];
//         z==2 -> V^T (Am=Wv, Bm=x swapped), write Vt[bh][d][s] (no rope).
// MODE 1: fp32 [M][N].
template <int MODE>
__global__ __launch_bounds__(512) void gemm_k(
    const u16* __restrict__ A,
    const u16* __restrict__ B0, const u16* __restrict__ B1, const u16* __restrict__ B2,
    void* __restrict__ C0, void* __restrict__ C1, void* __restrict__ C2,
    const float2* __restrict__ cs,
    int M, int N, int Kd)
{
    const int z = blockIdx.z;
    const u16* Am;
    const u16* Bm;
    int m0, n0;
    if (MODE == 0 && z == 2) {           // V^T = Wv @ x^T
        Am = B2; Bm = A;
        m0 = blockIdx.y * 128;           // over Wv rows (1024)
        n0 = blockIdx.x * 128;           // over tokens (4096)
    } else {
        Am = A;
        Bm = (z == 0) ? B0 : (z == 1) ? B1 : B2;
        m0 = blockIdx.x * 128;
        n0 = blockIdx.y * 128;
    }
    void* C = (z == 0) ? C0 : (z == 1) ? C1 : C2;

    __shared__ u16 sA[128 * 64];
    __shared__ u16 sB[128 * 64];

    const int t = threadIdx.x, l = t & 63, w = t >> 6;
    const int wm = w >> 2, wn = w & 3;            // 2M x 4N waves
    const int lr = l & 15, kg = l >> 4;

    f32x4 acc[4][2] = {};

    for (int k0 = 0; k0 < Kd; k0 += 64) {
        __syncthreads();
        // stage 2x16KB: linear dest (DMA lane rule), source granule pre-swizzled
#pragma unroll
        for (int p = 0; p < 2; ++p) {
            int i = p * 512 + t;
            int r = i >> 3;                       // row 0..127
            int gg = (i & 7) ^ (r & 7);           // source 16B-granule
            gload16(Am + (size_t)(m0 + r) * Kd + k0 + gg * 8, &sA[i * 8]);
            gload16(Bm + (size_t)(n0 + r) * Kd + k0 + gg * 8, &sB[i * 8]);
        }
        __syncthreads();

        bf16x8 af[4][2], bfr[2][2];
#pragma unroll
        for (int im = 0; im < 4; ++im) {
            int r = wm * 64 + im * 16 + lr;
#pragma unroll
            for (int ks = 0; ks < 2; ++ks) {
                int slot = (ks * 4 + kg) ^ (r & 7);
                af[im][ks] = *reinterpret_cast<const bf16x8*>(&sA[r * 64 + slot * 8]);
            }
        }
#pragma unroll
        for (int in = 0; in < 2; ++in) {
            int r = wn * 32 + in * 16 + lr;
#pragma unroll
            for (int ks = 0; ks < 2; ++ks) {
                int slot = (ks * 4 + kg) ^ (r & 7);
                bfr[in][ks] = *reinterpret_cast<const bf16x8*>(&sB[r * 64 + slot * 8]);
            }
        }
#pragma unroll
        for (int im = 0; im < 4; ++im)
#pragma unroll
            for (int in = 0; in < 2; ++in) {
                acc[im][in] = __builtin_amdgcn_mfma_f32_16x16x32_bf16(
                    af[im][0], bfr[in][0], acc[im][in], 0, 0, 0);
                acc[im][in] = __builtin_amdgcn_mfma_f32_16x16x32_bf16(
                    af[im][1], bfr[in][1], acc[im][in], 0, 0, 0);
            }
    }

#pragma unroll
    for (int im = 0; im < 4; ++im) {
#pragma unroll
        for (int in = 0; in < 2; ++in) {
#pragma unroll
            for (int j = 0; j < 4; ++j) {
                int row = m0 + wm * 64 + im * 16 + kg * 4 + j;
                int col = n0 + wn * 32 + in * 16 + lr;
                float v = acc[im][in][j];
                if (MODE == 0) {
                    if (z == 2) {
                        // V^T: row = h*64+d over 1024, col = b*2048+s over 4096
                        int h = row >> 6, d = row & 63;
                        int b = col >> 11, s = col & 2047;
                        ((u16*)C)[((size_t)((b * 16 + h) * 64 + d)) * 2048 + s] = f2bf(v);
                    } else {
                        // Q/K with fused RoPE; partner col^1 lives in lane l^1
                        float vp = __shfl_xor(v, 1);
                        int b = row >> 11, s = row & 2047;
                        int h = col >> 6, d = col & 63;
                        float2 c2 = cs[s * 64 + d];
                        float outv = (col & 1) ? (v * c2.x + vp * c2.y)
                                               : (v * c2.x - vp * c2.y);
                        ((u16*)C)[(((size_t)(b * 16 + h)) * 2048 + s) * 64 + d] = f2bf(outv);
                    }
                } else {
                    ((float*)C)[(size_t)row * N + col] = v;
                }
            }
        }
    }
}

// ---------- MFMA flash attention, window=256 — QBLK=128 (8 waves), KVBLK=64 ----------
// r16 optimum restored byte-for-byte: 128 q-rows per block (8 waves), kv-union
// = 6 tiles [2qt-4 .. 2qt+1]; per-query staging x0.6 vs QBLK=64, barriers x0.6.
// Waves with a fully-masked tile produce p=0 via the -1e20 guard (r10 path).
__global__ __launch_bounds__(512) void fattn(
    const u16* __restrict__ Qb, const u16* __restrict__ Kb,
    const u16* __restrict__ Vt, u16* __restrict__ O)
{
    __shared__ u16 sK[64 * 64];
    __shared__ u16 sVT[64 * 64];
    __shared__ u16 sP[8][16 * 64];

    const int t = threadIdx.x, l = t & 63, w = t >> 6;
    const int lo = l & 15, hi = l >> 4;
    const int qt = blockIdx.x, bh = blockIdx.y;
    const int q0 = qt * 128;

    // Q A-fragments direct from global (row 128B-contiguous, 16B/lane)
    bf16x8 qf[2];
    {
        const u16* Qr = Qb + ((size_t)bh * Ss + q0 + w * 16 + lo) * 64 + hi * 8;
#pragma unroll
        for (int ck = 0; ck < 2; ++ck)
            qf[ck] = *reinterpret_cast<const bf16x8*>(Qr + ck * 32);
    }

    f32x4 o[4] = {};
    float mj[4], lj[4];
#pragma unroll
    for (int j = 0; j < 4; ++j) { mj[j] = -1e30f; lj[j] = 0.f; }

    const int jt0 = (2 * qt >= 4) ? 2 * qt - 4 : 0;
    const int jt1 = 2 * qt + 1;
    for (int jt = jt0; jt <= jt1; ++jt) {
        __syncthreads();
        // ---- stage K tile (8 KB, 1 gload16/thread) ----
        const char* Kg = (const char*)(Kb + ((size_t)bh * Ss + jt * 64) * 64);
        {
            uint32_t x = (uint32_t)t * 16;
            uint32_t sx = x ^ (((x >> 7) & 7) << 4);
            gload16(Kg + sx, (char*)sK + x);
        }
        // ---- stage V^T tile from [bh][d][s] (row d: 4096B global stride) ----
        const char* Vg = (const char*)(Vt + (size_t)bh * 64 * 2048 + (size_t)jt * 64);
        {
            uint32_t x = (uint32_t)t * 16;
            uint32_t sx = x ^ (((x >> 7) & 7) << 4);
            gload16(Vg + (size_t)(x >> 7) * 4096 + (sx & 127), (char*)sVT + x);
        }
        __syncthreads();

        f32x4 s4[4] = {};
#pragma unroll
        for (int ck = 0; ck < 2; ++ck) {
#pragma unroll
            for (int nb = 0; nb < 4; ++nb) {
                uint32_t b = (uint32_t)(nb * 16 + lo) * 128 + ck * 64 + hi * 16;
                b ^= ((lo & 7) << 4);
                bf16x8 kf = *reinterpret_cast<const bf16x8*>((const char*)sK + b);
                s4[nb] = __builtin_amdgcn_mfma_f32_16x16x32_bf16(qf[ck], kf, s4[nb], 0, 0, 0);
            }
        }

        const int qbase = q0 + w * 16 + hi * 4;
#pragma unroll
        for (int nb = 0; nb < 4; ++nb) {
            int k = jt * 64 + nb * 16 + lo;
#pragma unroll
            for (int j = 0; j < 4; ++j) {
                int q = qbase + j;
                float v = s4[nb][j] * 0.125f;
                bool ok = (k <= q) && (q - k < Win);
                s4[nb][j] = ok ? v : -1e30f;
            }
        }

#pragma unroll
        for (int j = 0; j < 4; ++j) {
            float tm = fmaxf(fmaxf(s4[0][j], s4[1][j]), fmaxf(s4[2][j], s4[3][j]));
            tm = fmaxf(tm, __shfl_xor(tm, 1));
            tm = fmaxf(tm, __shfl_xor(tm, 2));
            tm = fmaxf(tm, __shfl_xor(tm, 4));
            tm = fmaxf(tm, __shfl_xor(tm, 8));
            float nm = fmaxf(fmaxf(mj[j], tm), -1e20f);
            float sc = __expf(mj[j] - nm);
            mj[j] = nm;
            lj[j] *= sc;
#pragma unroll
            for (int nb = 0; nb < 4; ++nb) o[nb][j] *= sc;
            float ps = 0.f;
#pragma unroll
            for (int nb = 0; nb < 4; ++nb) {
                float p = __expf(s4[nb][j] - nm);
                ps += p;
                s4[nb][j] = p;
            }
            lj[j] += ps;
        }

#pragma unroll
        for (int nb = 0; nb < 4; ++nb) {
#pragma unroll
            for (int j = 0; j < 4; ++j) {
                int r = hi * 4 + j;
                uint32_t b = ((uint32_t)r * 128 + (nb * 16 + lo) * 2) ^ (((uint32_t)(r & 7)) << 4);
                *(u16*)((char*)&sP[w][0] + b) = f2bf(s4[nb][j]);
            }
        }

#pragma unroll
        for (int ck = 0; ck < 2; ++ck) {
            uint32_t bp = ((uint32_t)lo * 128 + ck * 64 + hi * 16) ^ (((uint32_t)(lo & 7)) << 4);
            bf16x8 pa = *reinterpret_cast<const bf16x8*>((const char*)&sP[w][0] + bp);
#pragma unroll
            for (int nb = 0; nb < 4; ++nb) {
                uint32_t bb = ((uint32_t)(nb * 16 + lo) * 128 + ck * 64 + hi * 16) ^ (((uint32_t)(lo & 7)) << 4);
                bf16x8 vf = *reinterpret_cast<const bf16x8*>((const char*)sVT + bb);
                o[nb] = __builtin_amdgcn_mfma_f32_16x16x32_bf16(pa, vf, o[nb], 0, 0, 0);
            }
        }
    }

#pragma unroll
    for (int j = 0; j < 4; ++j) {
        float s = lj[j];
        s += __shfl_xor(s, 1);
        s += __shfl_xor(s, 2);
        s += __shfl_xor(s, 4);
        s += __shfl_xor(s, 8);
        lj[j] = 1.0f / s;
    }
    const int bq = bh >> 4, h = bh & 15;
#pragma unroll
    for (int nb = 0; nb < 4; ++nb) {
#pragma unroll
        for (int j = 0; j < 4; ++j) {
            int q = q0 + w * 16 + hi * 4 + j;
            int d = nb * 16 + lo;
            O[((size_t)(bq * Ss + q)) * Dd + h * 64 + d] = f2bf(o[nb][j] * lj[j]);
        }
    }
}

// ---------- launch ----------
extern "C" void kernel_launch(void* const* d_in, const int* in_sizes, int n_in,
                              void* d_out, int out_size, void* d_ws, size_t ws_size,
                              hipStream_t stream) {
    const float* x  = (const float*)d_in[0];
    const float* Wq = (const float*)d_in[1];
    const float* Wk = (const float*)d_in[2];
    const float* Wv = (const float*)d_in[3];
    const float* Wo = (const float*)d_in[4];
    float* out = (float*)d_out;

    char* ws = (char*)d_ws;
    size_t off = 0;
    auto carve = [&](size_t bytes) -> char* {
        char* p = ws + off;
        off += (bytes + 255) & ~(size_t)255;
        return p;
    };
    float2* cs = (float2*)carve((size_t)Ss * 64 * 8);
    u16* xb  = (u16*)carve((size_t)Mtot * Dd * 2);
    u16* wqb = (u16*)carve((size_t)Dd * Dd * 2);
    u16* wkb = (u16*)carve((size_t)Dd * Dd * 2);
    u16* wvb = (u16*)carve((size_t)Dd * Dd * 2);
    u16* wob = (u16*)carve((size_t)Dd * Dd * 2);
    u16* Qbb = (u16*)carve((size_t)Mtot * Dd * 2);
    u16* Kbb = (u16*)carve((size_t)Mtot * Dd * 2);
    u16* Vtb = (u16*)carve((size_t)Mtot * Dd * 2);   // V^T: [bh][d][s]
    u16* attb = (u16*)carve((size_t)Mtot * Dd * 2);

    prep<<<8704, 256, 0, stream>>>(x, Wq, Wk, Wv, Wo,
                                   xb, wqb, wkb, wvb, wob, cs);

    gemm_k<0><<<dim3(Mtot / 128, Dd / 128, 3), 512, 0, stream>>>(
        xb, wqb, wkb, wvb, Qbb, Kbb, Vtb, cs, Mtot, Dd, Dd);

    fattn<<<dim3(Ss / 128, Bb * Hh), 512, 0, stream>>>(Qbb, Kbb, Vtb, attb);

    gemm_k<1><<<dim3(Mtot / 128, Dd / 128, 1), 512, 0, stream>>>(
        attb, wob, wob, wob, out, out, out, nullptr, Mtot, Dd, Dd);
}